// Round 3
// baseline (2189.923 us; speedup 1.0000x reference)
//
#include <hip/hip_runtime.h>
#include <math.h>

#define S   30
#define FD  200
#define TT  1024
#define BB  1024
#define NC  7

// ---- workspace layout (float offsets), overlaid by live range ----
// C1 (conv1 out) [0, 31457280) dead after k_f2; then AF/GV/GH overlay it.
// F2 lives at 31457280 until k_mgcn done. Total 37,601,280 fl = 150.4 MB.
#define OFS_C1   0ull
#define OFS_F2   31457280ull
#define OFS_AF   0ull
#define OFS_GV   921600ull
#define OFS_GH   10137600ull
#define OFS_WCH  19353600ull
#define OFS_WFT  19384320ull

// ================= K1: conv1 + relu -> C1 =================
// Grid (8, B), 128 threads; thread = one time position, all 30 out-channels.
// Weights via wave-uniform addresses -> scalar loads.
__global__ __launch_bounds__(128) void k_conv1(
    const float* __restrict__ x,
    const float* __restrict__ Wc1, const float* __restrict__ bc1,
    float* __restrict__ C1) {
    const int c = blockIdx.x, b = blockIdx.y;
    const int tid = threadIdx.x;
    const int t0 = c * 128;
    __shared__ float xb[S * 130];   // x[t0-1 .. t0+128]
    for (int idx = tid; idx < S * 130; idx += 128) {
        int s = idx / 130, j = idx % 130;
        int gt = t0 - 1 + j;
        xb[idx] = (gt >= 0 && gt < TT) ? x[(b * S + s) * TT + gt] : 0.f;
    }
    __syncthreads();
    float acc[S];
#pragma unroll
    for (int so = 0; so < S; so++) acc[so] = bc1[so];
    for (int si = 0; si < S; si++) {
        float v0 = xb[si * 130 + tid], v1 = xb[si * 130 + tid + 1], v2 = xb[si * 130 + tid + 2];
        const float* w = Wc1 + si * 3;
#pragma unroll
        for (int so = 0; so < S; so++) {
            acc[so] = fmaf(w[so * 90 + 0], v0, acc[so]);
            acc[so] = fmaf(w[so * 90 + 1], v1, acc[so]);
            acc[so] = fmaf(w[so * 90 + 2], v2, acc[so]);
        }
    }
#pragma unroll
    for (int so = 0; so < S; so++)
        C1[(b * S + so) * TT + t0 + tid] = fmaxf(acc[so], 0.f);
}

// ================= K2: conv2 fused + F2 = relu(h2 @ Wt + bt) =================
// Per-b block. 16 chunks of 64 t-positions: conv2 tile -> LDS, then GEMM.
__global__ __launch_bounds__(256) void k_f2(
    const float* __restrict__ C1,
    const float* __restrict__ Wc2, const float* __restrict__ bc2,
    const float* __restrict__ Wt, const float* __restrict__ bt,
    float* __restrict__ F2) {
    const int b = blockIdx.x, t = threadIdx.x;
    __shared__ float c1t[S * 66];   // C1 chunk with halo 1
    __shared__ float xsl[S * 64];   // h2 chunk
    const int ct = t % 50, rt = t / 50;        // GEMM map (t<250): 4 cols, 6 rows
    const int c3 = t & 63, sg = t >> 6;        // conv2 map: col, 8-channel group
    float acc[6][4];
#pragma unroll
    for (int m = 0; m < 6; m++)
#pragma unroll
        for (int q = 0; q < 4; q++) acc[m][q] = 0.f;

    for (int ks = 0; ks < 16; ks++) {
        // load C1 tile with halo 1
        for (int idx = t; idx < S * 66; idx += 256) {
            int s = idx / 66, j = idx % 66;
            int gt = ks * 64 - 1 + j;
            c1t[idx] = (gt >= 0 && gt < TT) ? C1[(b * S + s) * TT + gt] : 0.f;
        }
        __syncthreads();
        // conv2 + relu -> xsl  (thread: 1 col x 8 out-channels)
        {
            float ac2[8];
#pragma unroll
            for (int m = 0; m < 8; m++) {
                int ss = sg * 8 + m;
                ac2[m] = bc2[ss < S ? ss : S - 1];
            }
            for (int si = 0; si < S; si++) {
                float v0 = c1t[si * 66 + c3], v1 = c1t[si * 66 + c3 + 1], v2 = c1t[si * 66 + c3 + 2];
#pragma unroll
                for (int m = 0; m < 8; m++) {
                    int ss = sg * 8 + m;
                    const float* w = Wc2 + (ss < S ? ss : S - 1) * 90 + si * 3;
                    ac2[m] = fmaf(w[0], v0, fmaf(w[1], v1, fmaf(w[2], v2, ac2[m])));
                }
            }
#pragma unroll
            for (int m = 0; m < 8; m++) {
                int ss = sg * 8 + m;
                if (ss < S) xsl[ss * 64 + c3] = fmaxf(ac2[m], 0.f);
            }
        }
        __syncthreads();
        // GEMM partial: acc += h2chunk @ Wt[ks*64 : ks*64+64, :]
        if (t < 250) {
#pragma unroll 2
            for (int kk = 0; kk < 64; kk++) {
                const float4 w = *(const float4*)(Wt + (ks * 64 + kk) * FD + 4 * ct);
#pragma unroll
                for (int m = 0; m < 6; m++) {
                    float a = xsl[(rt * 6 + m) * 64 + kk];
                    acc[m][0] = fmaf(a, w.x, acc[m][0]);
                    acc[m][1] = fmaf(a, w.y, acc[m][1]);
                    acc[m][2] = fmaf(a, w.z, acc[m][2]);
                    acc[m][3] = fmaf(a, w.w, acc[m][3]);
                }
            }
        }
        __syncthreads();
    }
    if (t < 250) {
#pragma unroll
        for (int m = 0; m < 6; m++) {
            int row = rt * 6 + m;
            float4 o;
            o.x = fmaxf(acc[m][0] + bt[4 * ct + 0], 0.f);
            o.y = fmaxf(acc[m][1] + bt[4 * ct + 1], 0.f);
            o.z = fmaxf(acc[m][2] + bt[4 * ct + 2], 0.f);
            o.w = fmaxf(acc[m][3] + bt[4 * ct + 3], 0.f);
            *(float4*)(F2 + (size_t)(b * S + row) * FD + 4 * ct) = o;
        }
    }
}

// ------------- GEMM helpers (30-row tiles, LDS X, global W) -------------
template<int RPT>
__device__ inline void zacc(float acc[][4]) {
#pragma unroll
    for (int m = 0; m < RPT; m++)
#pragma unroll
        for (int q = 0; q < 4; q++) acc[m][q] = 0.f;
}

// acc[m][q] += sum_k Xl[(rt*RPT+m)*xstr + k] * W[k*N + 4ct + q]
template<int RPT>
__device__ inline void gemm_w4(const float* Xl, int xstr, const float* __restrict__ W,
                               int N, int K, int ct, int rt, float acc[][4]) {
#pragma unroll 2
    for (int k = 0; k < K; k++) {
        const float4 w = *(const float4*)(W + k * N + 4 * ct);
#pragma unroll
        for (int m = 0; m < RPT; m++) {
            float a = Xl[(rt * RPT + m) * xstr + k];
            acc[m][0] = fmaf(a, w.x, acc[m][0]);
            acc[m][1] = fmaf(a, w.y, acc[m][1]);
            acc[m][2] = fmaf(a, w.z, acc[m][2]);
            acc[m][3] = fmaf(a, w.w, acc[m][3]);
        }
    }
}

// acc[m][q] += sum_k Al[(rt*RPT+m)*S + k] * Xl[k*xstr + 4ct + q]
template<int RPT>
__device__ inline void gemm_a(const float* Al, const float* Xl, int xstr,
                              int ct, int rt, float acc[][4]) {
#pragma unroll 2
    for (int k = 0; k < S; k++) {
        const float4 xv = *(const float4*)(Xl + k * xstr + 4 * ct);
#pragma unroll
        for (int m = 0; m < RPT; m++) {
            float a = Al[(rt * RPT + m) * S + k];
            acc[m][0] = fmaf(a, xv.x, acc[m][0]);
            acc[m][1] = fmaf(a, xv.y, acc[m][1]);
            acc[m][2] = fmaf(a, xv.z, acc[m][2]);
            acc[m][3] = fmaf(a, xv.w, acc[m][3]);
        }
    }
}

// N=150 map: t<228, ct2=t%38 (last group 2 cols), rt2=t/38, RPT=5
__device__ inline void gemm_w150(const float* Xl, const float* __restrict__ W,
                                 int ct2, int rt2, float acc[5][4], bool full) {
#pragma unroll 2
    for (int k = 0; k < FD; k++) {
        const float* wr = W + k * 150 + 4 * ct2;
        float2 w01 = *(const float2*)(wr);
        float2 w23 = full ? *(const float2*)(wr + 2) : make_float2(0.f, 0.f);
#pragma unroll
        for (int m = 0; m < 5; m++) {
            float a = Xl[(rt2 * 5 + m) * FD + k];
            acc[m][0] = fmaf(a, w01.x, acc[m][0]);
            acc[m][1] = fmaf(a, w01.y, acc[m][1]);
            acc[m][2] = fmaf(a, w23.x, acc[m][2]);
            acc[m][3] = fmaf(a, w23.y, acc[m][3]);
        }
    }
}

// ================= K3: k_att = AF + Gv(loc|glb) =================
__global__ __launch_bounds__(256) void k_att(
    const float* __restrict__ F2, const float* __restrict__ Wa,
    const float* __restrict__ adj, const float* __restrict__ Wl,
    const float* __restrict__ Wgl,
    float* __restrict__ AF, float* __restrict__ Gv) {
    const int b = blockIdx.x, t = threadIdx.x;
    __shared__ float A[S * FD];      // F2
    __shared__ float Bu[S * FD];     // P / T staging
    __shared__ float sc[S * S];      // scores -> A_F
    __shared__ float adjl[S * S];
    for (int idx = t; idx < S * FD; idx += 256) A[idx] = F2[(size_t)b * S * FD + idx];
    for (int idx = t; idx < S * S; idx += 256) adjl[idx] = adj[idx];
    __syncthreads();
    const int ct = t % 50, rt = t / 50;
    float acc[6][4];
    // P = F2 @ Wa -> Bu
    zacc<6>(acc);
    if (t < 250) {
        gemm_w4<6>(A, FD, Wa, FD, FD, ct, rt, acc);
#pragma unroll
        for (int m = 0; m < 6; m++) {
            float4 o = {acc[m][0], acc[m][1], acc[m][2], acc[m][3]};
            *(float4*)(Bu + (rt * 6 + m) * FD + 4 * ct) = o;
        }
    }
    __syncthreads();
    // sc[i,j] = relu(P[i,:] . F2[j,:])
    for (int idx = t; idx < S * S; idx += 256) {
        int i = idx / S, j = idx % S;
        float a = 0.f;
        for (int f4 = 0; f4 < 50; f4++) {
            float4 p = *(const float4*)(Bu + i * FD + 4 * f4);
            float4 q = *(const float4*)(A + j * FD + 4 * f4);
            a = fmaf(p.x, q.x, a); a = fmaf(p.y, q.y, a);
            a = fmaf(p.z, q.z, a); a = fmaf(p.w, q.w, a);
        }
        sc[idx] = fmaxf(a, 0.f);
    }
    __syncthreads();
    // softmax rows, in place
    if (t < S) {
        float mx = -1e30f;
        for (int j = 0; j < S; j++) mx = fmaxf(mx, sc[t * S + j]);
        float den = 0.f;
        for (int j = 0; j < S; j++) den += expf(sc[t * S + j] - mx);
        float inv = 1.f / den;
        for (int j = 0; j < S; j++) sc[t * S + j] = expf(sc[t * S + j] - mx) * inv;
    }
    __syncthreads();
    for (int idx = t; idx < S * S; idx += 256) AF[(size_t)b * S * S + idx] = sc[idx];
    // loc: T = adj @ F2 -> Bu ; Gv[:, :150] = relu(T @ Wl)
    zacc<6>(acc);
    if (t < 250) gemm_a<6>(adjl, A, FD, ct, rt, acc);
    __syncthreads();
    if (t < 250)
#pragma unroll
        for (int m = 0; m < 6; m++) {
            float4 o = {acc[m][0], acc[m][1], acc[m][2], acc[m][3]};
            *(float4*)(Bu + (rt * 6 + m) * FD + 4 * ct) = o;
        }
    __syncthreads();
    const int ct2 = t % 38, rt2 = t / 38;
    if (t < 228) {
        bool full = (4 * ct2 + 2) < 150;
        float a2[5][4];
        zacc<5>(a2);
        gemm_w150(Bu, Wl, ct2, rt2, a2, full);
#pragma unroll
        for (int m = 0; m < 5; m++) {
            float* o = Gv + (size_t)(b * S + rt2 * 5 + m) * 300 + 4 * ct2;
            o[0] = fmaxf(a2[m][0], 0.f); o[1] = fmaxf(a2[m][1], 0.f);
            if (full) { o[2] = fmaxf(a2[m][2], 0.f); o[3] = fmaxf(a2[m][3], 0.f); }
        }
    }
    __syncthreads();
    // glb: T = AF @ F2 -> Bu ; Gv[:, 150:] = relu(T @ Wgl)
    zacc<6>(acc);
    if (t < 250) gemm_a<6>(sc, A, FD, ct, rt, acc);
    __syncthreads();
    if (t < 250)
#pragma unroll
        for (int m = 0; m < 6; m++) {
            float4 o = {acc[m][0], acc[m][1], acc[m][2], acc[m][3]};
            *(float4*)(Bu + (rt * 6 + m) * FD + 4 * ct) = o;
        }
    __syncthreads();
    if (t < 228) {
        bool full = (4 * ct2 + 2) < 150;
        float a2[5][4];
        zacc<5>(a2);
        gemm_w150(Bu, Wgl, ct2, rt2, a2, full);
#pragma unroll
        for (int m = 0; m < 5; m++) {
            float* o = Gv + (size_t)(b * S + rt2 * 5 + m) * 300 + 150 + 4 * ct2;
            o[0] = fmaxf(a2[m][0], 0.f); o[1] = fmaxf(a2[m][1], 0.f);
            if (full) { o[2] = fmaxf(a2[m][2], 0.f); o[3] = fmaxf(a2[m][3], 0.f); }
        }
    }
}

// ================= K4: k_mgcn = xs + X1..X3 + gates + Gh =================
__global__ __launch_bounds__(256) void k_mgcn(
    const float* __restrict__ F2, const float* __restrict__ AF,
    const float* __restrict__ adj,
    const float* __restrict__ Wg1, const float* __restrict__ Wg2,
    const float* __restrict__ Wm1, const float* __restrict__ Wm2,
    const float* __restrict__ Wm3, const float* __restrict__ wg,
    const float* __restrict__ Wp1, const float* __restrict__ Wp2,
    const float* __restrict__ Wp3, float* __restrict__ Gh) {
    const int b = blockIdx.x, t = threadIdx.x;
    __shared__ float A[S * FD];      // X chain (starts as F2)
    __shared__ float Bu[S * FD];     // xs, then T staging in Gh phase
    __shared__ float afl[S * S];     // AF, then adj*g_k in Gh phase
    __shared__ float adjl[S * S];
    __shared__ float scp[S * 50];    // score partials
    __shared__ float sk[S * 3 + 2];
    __shared__ float gl[S * 3 + 2];
    const int ct = t % 50, rt = t / 50;
    const int ct3 = t % 25, rt3 = t / 25;
    for (int idx = t; idx < S * FD; idx += 256) A[idx] = F2[(size_t)b * S * FD + idx];
    for (int idx = t; idx < S * S; idx += 256) {
        afl[idx] = AF[(size_t)b * S * S + idx];
        adjl[idx] = adj[idx];
    }
    __syncthreads();

    float acc[6][4];
    // helper macros (in-place safe: accumulate -> sync -> write -> sync)
#define STAGE_A(AL, XIN, XOUT)                                              \
    {                                                                       \
        zacc<6>(acc);                                                       \
        if (t < 250) gemm_a<6>(AL, XIN, FD, ct, rt, acc);                   \
        __syncthreads();                                                    \
        if (t < 250) {                                                      \
            _Pragma("unroll")                                               \
            for (int m = 0; m < 6; m++) {                                   \
                float4 o = {acc[m][0], acc[m][1], acc[m][2], acc[m][3]};    \
                *(float4*)(XOUT + (rt * 6 + m) * FD + 4 * ct) = o;          \
            }                                                               \
        }                                                                   \
        __syncthreads();                                                    \
    }
#define STAGE_W(XIN, W, XOUT, RELU)                                         \
    {                                                                       \
        zacc<6>(acc);                                                       \
        if (t < 250) gemm_w4<6>(XIN, FD, W, FD, FD, ct, rt, acc);           \
        __syncthreads();                                                    \
        if (t < 250) {                                                      \
            _Pragma("unroll")                                               \
            for (int m = 0; m < 6; m++) {                                   \
                float4 o;                                                   \
                o.x = RELU ? fmaxf(acc[m][0], 0.f) : acc[m][0];             \
                o.y = RELU ? fmaxf(acc[m][1], 0.f) : acc[m][1];             \
                o.z = RELU ? fmaxf(acc[m][2], 0.f) : acc[m][2];             \
                o.w = RELU ? fmaxf(acc[m][3], 0.f) : acc[m][3];             \
                *(float4*)(XOUT + (rt * 6 + m) * FD + 4 * ct) = o;          \
            }                                                               \
        }                                                                   \
        __syncthreads();                                                    \
    }

    // xs chain in Bu: P=adj@F2; h=relu(P@Wg1); q=adj@h; xs=q@Wg2
    STAGE_A(adjl, A, Bu);
    STAGE_W(Bu, Wg1, Bu, true);
    STAGE_A(adjl, Bu, Bu);
    STAGE_W(Bu, Wg2, Bu, false);

    float h1r[6][4], h2r[6][4], h3r[6][4];
#define EXTRACT_H(HR, K)                                                    \
    {                                                                       \
        if (t < 250) {                                                      \
            _Pragma("unroll")                                               \
            for (int m = 0; m < 6; m++) {                                   \
                int row = rt * 6 + m;                                       \
                float4 xv = *(const float4*)(A + row * FD + 4 * ct);        \
                float4 sv = *(const float4*)(Bu + row * FD + 4 * ct);       \
                HR[m][0] = 0.5f * (xv.x + sv.x);                            \
                HR[m][1] = 0.5f * (xv.y + sv.y);                            \
                HR[m][2] = 0.5f * (xv.z + sv.z);                            \
                HR[m][3] = 0.5f * (xv.w + sv.w);                            \
            }                                                               \
            _Pragma("unroll")                                               \
            for (int m = 0; m < 6; m++) {                                   \
                float p = HR[m][0] * wg[(4 * ct + 0) * 3 + K]               \
                        + HR[m][1] * wg[(4 * ct + 1) * 3 + K]               \
                        + HR[m][2] * wg[(4 * ct + 2) * 3 + K]               \
                        + HR[m][3] * wg[(4 * ct + 3) * 3 + K];              \
                scp[(rt * 6 + m) * 50 + ct] = p;                            \
            }                                                               \
        }                                                                   \
        __syncthreads();                                                    \
        if (t < S) {                                                        \
            float s_ = 0.f;                                                 \
            for (int c_ = 0; c_ < 50; c_++) s_ += scp[t * 50 + c_];         \
            sk[t * 3 + K] = s_;                                             \
        }                                                                   \
        __syncthreads();                                                    \
    }

    // X chain in A (in place): X_k = relu((AF @ X_{k-1}) @ Wm_k); H_k in regs
    STAGE_A(afl, A, A);
    STAGE_W(A, Wm1, A, true);
    EXTRACT_H(h1r, 0);
    STAGE_A(afl, A, A);
    STAGE_W(A, Wm2, A, true);
    EXTRACT_H(h2r, 1);
    STAGE_A(afl, A, A);
    STAGE_W(A, Wm3, A, true);
    EXTRACT_H(h3r, 2);

    // gates
    if (t < S) {
        float a0 = sk[t * 3 + 0], a1 = sk[t * 3 + 1], a2 = sk[t * 3 + 2];
        float m = fmaxf(a0, fmaxf(a1, a2));
        float e0 = expf(a0 - m), e1 = expf(a1 - m), e2 = expf(a2 - m);
        float inv = 1.f / (e0 + e1 + e2);
        gl[t * 3 + 0] = e0 * inv; gl[t * 3 + 1] = e1 * inv; gl[t * 3 + 2] = e2 * inv;
    }
    __syncthreads();

    // Gh phase: for k: A<-H_k, afl<-adj*g_k; T=afl@A->Bu; Gh_k = T@Wp_k
#define GH_STAGE(HR, K, WP)                                                 \
    {                                                                       \
        if (t < 250) {                                                      \
            _Pragma("unroll")                                               \
            for (int m = 0; m < 6; m++) {                                   \
                float4 o = {HR[m][0], HR[m][1], HR[m][2], HR[m][3]};        \
                *(float4*)(A + (rt * 6 + m) * FD + 4 * ct) = o;             \
            }                                                               \
        }                                                                   \
        for (int idx = t; idx < S * S; idx += 256)                          \
            afl[idx] = adjl[idx] * gl[(idx % S) * 3 + K];                   \
        __syncthreads();                                                    \
        zacc<6>(acc);                                                       \
        if (t < 250) gemm_a<6>(afl, A, FD, ct, rt, acc);                    \
        __syncthreads();                                                    \
        if (t < 250) {                                                      \
            _Pragma("unroll")                                               \
            for (int m = 0; m < 6; m++) {                                   \
                float4 o = {acc[m][0], acc[m][1], acc[m][2], acc[m][3]};    \
                *(float4*)(Bu + (rt * 6 + m) * FD + 4 * ct) = o;            \
            }                                                               \
        }                                                                   \
        __syncthreads();                                                    \
        if (t < 250) {                                                      \
            float a3[3][4];                                                 \
            zacc<3>(a3);                                                    \
            gemm_w4<3>(Bu, FD, WP, 100, FD, ct3, rt3, a3);                  \
            _Pragma("unroll")                                               \
            for (int m = 0; m < 3; m++) {                                   \
                float4 o = {a3[m][0], a3[m][1], a3[m][2], a3[m][3]};        \
                *(float4*)(Gh + (size_t)(b * S + rt3 * 3 + m) * 300 + K * 100 + 4 * ct3) = o; \
            }                                                               \
        }                                                                   \
        __syncthreads();                                                    \
    }
    GH_STAGE(h1r, 0, Wp1);
    GH_STAGE(h2r, 1, Wp2);
    GH_STAGE(h3r, 2, Wp3);
#undef STAGE_A
#undef STAGE_W
#undef EXTRACT_H
#undef GH_STAGE
}

// ================= K5: SE gates =================
__global__ __launch_bounds__(256) void k_se(const float* __restrict__ Gv, const float* __restrict__ Gh,
                                            const float* __restrict__ Ws1, const float* __restrict__ Ws2,
                                            const float* __restrict__ Wf1, const float* __restrict__ Wf2,
                                            float* __restrict__ wch, float* __restrict__ wft) {
    int b = blockIdx.x, t = threadIdx.x;
    __shared__ float mrow[S];
    __shared__ float u[15];
    __shared__ float mb[300];
    __shared__ float v[150];
    if (t < S) {
        float a = 0.f;
        const float* gp = Gv + ((size_t)b * S + t) * 300;
        for (int j = 0; j < 300; j++) a += gp[j];
        mrow[t] = a * (1.f / 300.f);
    }
    for (int j = t; j < 300; j += 256) {
        float a = 0.f;
        for (int s = 0; s < S; s++) a += Gh[(size_t)b * S * 300 + s * 300 + j];
        mb[j] = a * (1.f / S);
    }
    __syncthreads();
    if (t < 15) {
        float a = 0.f;
        for (int i = 0; i < S; i++) a += mrow[i] * Ws1[i * 15 + t];
        u[t] = fmaxf(a, 0.f);
    }
    if (t >= 64 && t < 64 + 150) {
        int h = t - 64;
        float a = 0.f;
        for (int j = 0; j < 300; j++) a += mb[j] * Wf1[j * 150 + h];
        v[h] = fmaxf(a, 0.f);
    }
    __syncthreads();
    if (t < S) {
        float a = 0.f;
        for (int h = 0; h < 15; h++) a += u[h] * Ws2[h * 30 + t];
        wch[b * S + t] = 1.f / (1.f + expf(-a));
    }
    for (int j = t; j < 300; j += 256) {
        float a = 0.f;
        for (int h = 0; h < 150; h++) a += v[h] * Wf2[h * 300 + j];
        wft[b * 300 + j] = 1.f / (1.f + expf(-a));
    }
}

// ================= K6: classifier + log_softmax (per-b block) =================
__global__ __launch_bounds__(256) void k_cls(const float* __restrict__ Gh, const float* __restrict__ Gv,
                                             const float* __restrict__ wch, const float* __restrict__ wft,
                                             const float* __restrict__ Wcls, const float* __restrict__ bcls,
                                             float* __restrict__ out) {
    const int b = blockIdx.x, t = threadIdx.x;
    __shared__ float red[NC][256];
    __shared__ float wftl[300];
    __shared__ float wchl[S];
    for (int j = t; j < 300; j += 256) wftl[j] = wft[(size_t)b * 300 + j];
    if (t < S) wchl[t] = wch[b * S + t];
    __syncthreads();
    float acc[NC];
#pragma unroll
    for (int c = 0; c < NC; c++) acc[c] = 0.f;
    for (int i = t; i < S * 600; i += 256) {
        int s = i / 600, j = i % 600;
        float gval = (j < 300)
            ? Gh[(size_t)b * S * 300 + s * 300 + j] * wchl[s]
            : Gv[(size_t)b * S * 300 + s * 300 + (j - 300)] * wftl[j - 300];
        const float* wr = Wcls + (size_t)i * NC;
#pragma unroll
        for (int c = 0; c < NC; c++) acc[c] = fmaf(gval, wr[c], acc[c]);
    }
#pragma unroll
    for (int c = 0; c < NC; c++) red[c][t] = acc[c];
    __syncthreads();
    for (int off = 128; off > 0; off >>= 1) {
        if (t < off) {
#pragma unroll
            for (int c = 0; c < NC; c++) red[c][t] += red[c][t + off];
        }
        __syncthreads();
    }
    if (t == 0) {
        float lg[NC];
        float mx = -1e30f;
#pragma unroll
        for (int c = 0; c < NC; c++) { lg[c] = red[c][0] + bcls[c]; mx = fmaxf(mx, lg[c]); }
        float den = 0.f;
#pragma unroll
        for (int c = 0; c < NC; c++) den += expf(lg[c] - mx);
        float lden = logf(den) + mx;
#pragma unroll
        for (int c = 0; c < NC; c++) out[b * NC + c] = lg[c] - lden;
    }
}

extern "C" void kernel_launch(void* const* d_in, const int* in_sizes, int n_in,
                              void* d_out, int out_size, void* d_ws, size_t ws_size,
                              hipStream_t stream) {
    const float* x    = (const float*)d_in[0];
    const float* adj  = (const float*)d_in[1];
    const float* Wc1  = (const float*)d_in[2];
    const float* bc1  = (const float*)d_in[3];
    const float* Wc2  = (const float*)d_in[4];
    const float* bc2  = (const float*)d_in[5];
    const float* Wt   = (const float*)d_in[6];
    const float* bt   = (const float*)d_in[7];
    const float* Wa   = (const float*)d_in[8];
    const float* Wm1  = (const float*)d_in[9];
    const float* Wm2  = (const float*)d_in[10];
    const float* Wm3  = (const float*)d_in[11];
    const float* Wg1  = (const float*)d_in[12];
    const float* Wg2  = (const float*)d_in[13];
    const float* wg   = (const float*)d_in[14];
    const float* Wp1  = (const float*)d_in[15];
    const float* Wp2  = (const float*)d_in[16];
    const float* Wp3  = (const float*)d_in[17];
    const float* Wl   = (const float*)d_in[18];
    const float* Wgl  = (const float*)d_in[19];
    const float* Ws1  = (const float*)d_in[20];
    const float* Ws2  = (const float*)d_in[21];
    const float* Wf1  = (const float*)d_in[22];
    const float* Wf2  = (const float*)d_in[23];
    const float* Wcls = (const float*)d_in[24];
    const float* bcls = (const float*)d_in[25];

    float* ws  = (float*)d_ws;
    float* C1  = ws + OFS_C1;
    float* F2  = ws + OFS_F2;
    float* AF  = ws + OFS_AF;
    float* GV  = ws + OFS_GV;
    float* GH  = ws + OFS_GH;
    float* WCH = ws + OFS_WCH;
    float* WFT = ws + OFS_WFT;
    float* out = (float*)d_out;

    k_conv1<<<dim3(8, BB), 128, 0, stream>>>(x, Wc1, bc1, C1);
    k_f2<<<BB, 256, 0, stream>>>(C1, Wc2, bc2, Wt, bt, F2);
    k_att<<<BB, 256, 0, stream>>>(F2, Wa, adj, Wl, Wgl, AF, GV);
    k_mgcn<<<BB, 256, 0, stream>>>(F2, AF, adj, Wg1, Wg2, Wm1, Wm2, Wm3, wg,
                                   Wp1, Wp2, Wp3, GH);
    k_se<<<BB, 256, 0, stream>>>(GV, GH, Ws1, Ws2, Wf1, Wf2, WCH, WFT);
    k_cls<<<BB, 256, 0, stream>>>(GH, GV, WCH, WFT, Wcls, bcls, out);
}

// Round 4
// 1399.900 us; speedup vs baseline: 1.5643x; 1.5643x over previous
//
#include <hip/hip_runtime.h>
#include <math.h>

#define S   30
#define FD  200
#define TT  1024
#define BB  1024
#define NC  7

// ---- workspace layout (float offsets), overlaid by live range ----
#define OFS_C1   0ull
#define OFS_F2   31457280ull
#define OFS_AF   0ull
#define OFS_GV   921600ull
#define OFS_GH   10137600ull
#define OFS_WCH  19353600ull
#define OFS_WFT  19384320ull
// total 37,601,280 floats = 150.4 MB (known-safe ws size)

// ================= K1: conv1 + relu -> C1 =================
// Grid (4, B), 128 threads; thread = 2 time positions x 30 out-channels.
// 2 FMAs per scalar weight load.
__global__ __launch_bounds__(128) void k_conv1(
    const float* __restrict__ x,
    const float* __restrict__ Wc1, const float* __restrict__ bc1,
    float* __restrict__ C1) {
    const int c = blockIdx.x, b = blockIdx.y;
    const int tid = threadIdx.x;
    const int t0 = c * 256;
    __shared__ float xb[S * 258];   // cols t0-1 .. t0+256
    for (int idx = tid; idx < S * 258; idx += 128) {
        int s = idx / 258, j = idx % 258;
        int gt = t0 - 1 + j;
        xb[idx] = (gt >= 0 && gt < TT) ? x[(b * S + s) * TT + gt] : 0.f;
    }
    __syncthreads();
    float acc0[S], acc1[S];
#pragma unroll
    for (int so = 0; so < S; so++) { acc0[so] = bc1[so]; acc1[so] = bc1[so]; }
    const int p = 2 * tid;
    for (int si = 0; si < S; si++) {
        float2 va = *(const float2*)(xb + si * 258 + p);
        float2 vb = *(const float2*)(xb + si * 258 + p + 2);
        const float* w = Wc1 + si * 3;
#pragma unroll
        for (int so = 0; so < S; so++) {
            float w0 = w[so * 90 + 0], w1 = w[so * 90 + 1], w2 = w[so * 90 + 2];
            acc0[so] = fmaf(w0, va.x, fmaf(w1, va.y, fmaf(w2, vb.x, acc0[so])));
            acc1[so] = fmaf(w0, va.y, fmaf(w1, vb.x, fmaf(w2, vb.y, acc1[so])));
        }
    }
#pragma unroll
    for (int so = 0; so < S; so++) {
        float2 o = {fmaxf(acc0[so], 0.f), fmaxf(acc1[so], 0.f)};
        *(float2*)(C1 + (size_t)(b * S + so) * TT + t0 + p) = o;
    }
}

// ---------- FMA tile helpers ----------
#define FMA4(av, wv, accm)                           \
    {                                                \
        accm[0] = fmaf(av, (wv).x, accm[0]);         \
        accm[1] = fmaf(av, (wv).y, accm[1]);         \
        accm[2] = fmaf(av, (wv).z, accm[2]);         \
        accm[3] = fmaf(av, (wv).w, accm[3]);         \
    }

__device__ inline void fma_tile8(const float4 a0, const float4 a1,
                                 const float4 w[8], float accm[4]) {
    FMA4(a0.x, w[0], accm); FMA4(a0.y, w[1], accm);
    FMA4(a0.z, w[2], accm); FMA4(a0.w, w[3], accm);
    FMA4(a1.x, w[4], accm); FMA4(a1.y, w[5], accm);
    FMA4(a1.z, w[6], accm); FMA4(a1.w, w[7], accm);
}

template<int RPT>
__device__ inline void zacc(float acc[][4]) {
#pragma unroll
    for (int m = 0; m < RPT; m++)
#pragma unroll
        for (int q = 0; q < 4; q++) acc[m][q] = 0.f;
}

// ---------- gemm_w4_pf: X(LDS) @ W(global), depth-8 register pipeline ----------
// acc[m][0..3] += sum_k Xl[(rt*RPT+m)*xstr + k] * W[k*N + 4ct + 0..3]
template<int RPT, int N, int K>
__device__ inline void gemm_w4_pf(const float* Xl, int xstr, const float* __restrict__ W,
                                  int ct, int rt, float acc[][4]) {
    const float* wp = W + 4 * ct;
    float4 wreg[8];
#pragma unroll
    for (int u = 0; u < 8; u++) wreg[u] = *(const float4*)(wp + u * N);
#pragma unroll 1
    for (int kt = 0; kt < K / 8 - 1; kt++) {
        float4 wnxt[8];
#pragma unroll
        for (int u = 0; u < 8; u++) wnxt[u] = *(const float4*)(wp + (kt * 8 + 8 + u) * N);
#pragma unroll
        for (int m = 0; m < RPT; m++) {
            const float* xr = Xl + (rt * RPT + m) * xstr + kt * 8;
            float4 a0 = *(const float4*)(xr);
            float4 a1 = *(const float4*)(xr + 4);
            fma_tile8(a0, a1, wreg, acc[m]);
        }
#pragma unroll
        for (int u = 0; u < 8; u++) wreg[u] = wnxt[u];
    }
    {
        const int kb = K - 8;
#pragma unroll
        for (int m = 0; m < RPT; m++) {
            const float* xr = Xl + (rt * RPT + m) * xstr + kb;
            float4 a0 = *(const float4*)(xr);
            float4 a1 = *(const float4*)(xr + 4);
            fma_tile8(a0, a1, wreg, acc[m]);
        }
    }
}

// ---------- gemm_a32: Al(LDS, stride 32, K padded to 32) @ Xl(LDS) ----------
// acc[m][q] += sum_{k<32} Al[(rt*RPT+m)*32 + k] * Xl[k*xstr + 4ct + q]
template<int RPT>
__device__ inline void gemm_a32(const float* Al, const float* Xl, int xstr,
                                int ct, int rt, float acc[][4]) {
#pragma unroll
    for (int k4 = 0; k4 < 8; k4++) {
        float4 xv0 = *(const float4*)(Xl + (4 * k4 + 0) * xstr + 4 * ct);
        float4 xv1 = *(const float4*)(Xl + (4 * k4 + 1) * xstr + 4 * ct);
        float4 xv2 = *(const float4*)(Xl + (4 * k4 + 2) * xstr + 4 * ct);
        float4 xv3 = *(const float4*)(Xl + (4 * k4 + 3) * xstr + 4 * ct);
#pragma unroll
        for (int m = 0; m < RPT; m++) {
            float4 av = *(const float4*)(Al + (rt * RPT + m) * 32 + 4 * k4);
            FMA4(av.x, xv0, acc[m]);
            FMA4(av.y, xv1, acc[m]);
            FMA4(av.z, xv2, acc[m]);
            FMA4(av.w, xv3, acc[m]);
        }
    }
}

// ---------- gemm_w150_pf: N=150, float2-pair columns, depth-8 pipeline ----------
__device__ inline void gemm_w150_pf(const float* Xl, const float* __restrict__ W,
                                    int ct2, int rt2, float acc[5][4], int off23) {
    const float* wp = W + 4 * ct2;
    float2 wa[8], wb[8];
#pragma unroll
    for (int u = 0; u < 8; u++) {
        wa[u] = *(const float2*)(wp + u * 150);
        wb[u] = *(const float2*)(wp + u * 150 + off23);
    }
#pragma unroll 1
    for (int kt = 0; kt < 24; kt++) {
        float2 na[8], nb[8];
#pragma unroll
        for (int u = 0; u < 8; u++) {
            int k = kt * 8 + 8 + u;
            na[u] = *(const float2*)(wp + k * 150);
            nb[u] = *(const float2*)(wp + k * 150 + off23);
        }
#pragma unroll
        for (int m = 0; m < 5; m++) {
            const float* xr = Xl + (rt2 * 5 + m) * FD + kt * 8;
            float4 a0 = *(const float4*)(xr);
            float4 a1 = *(const float4*)(xr + 4);
            float av[8] = {a0.x, a0.y, a0.z, a0.w, a1.x, a1.y, a1.z, a1.w};
#pragma unroll
            for (int u = 0; u < 8; u++) {
                acc[m][0] = fmaf(av[u], wa[u].x, acc[m][0]);
                acc[m][1] = fmaf(av[u], wa[u].y, acc[m][1]);
                acc[m][2] = fmaf(av[u], wb[u].x, acc[m][2]);
                acc[m][3] = fmaf(av[u], wb[u].y, acc[m][3]);
            }
        }
#pragma unroll
        for (int u = 0; u < 8; u++) { wa[u] = na[u]; wb[u] = nb[u]; }
    }
#pragma unroll
    for (int m = 0; m < 5; m++) {
        const float* xr = Xl + (rt2 * 5 + m) * FD + 192;
        float4 a0 = *(const float4*)(xr);
        float4 a1 = *(const float4*)(xr + 4);
        float av[8] = {a0.x, a0.y, a0.z, a0.w, a1.x, a1.y, a1.z, a1.w};
#pragma unroll
        for (int u = 0; u < 8; u++) {
            acc[m][0] = fmaf(av[u], wa[u].x, acc[m][0]);
            acc[m][1] = fmaf(av[u], wa[u].y, acc[m][1]);
            acc[m][2] = fmaf(av[u], wb[u].x, acc[m][2]);
            acc[m][3] = fmaf(av[u], wb[u].y, acc[m][3]);
        }
    }
}

// ================= K2: conv2 fused + F2 = relu(h2 @ Wt + bt) =================
// Per-b block, 256 threads, 8 chunks of 128 t-positions.
__global__ __launch_bounds__(256) void k_f2(
    const float* __restrict__ C1,
    const float* __restrict__ Wc2, const float* __restrict__ bc2,
    const float* __restrict__ Wt, const float* __restrict__ bt,
    float* __restrict__ F2) {
    const int b = blockIdx.x, t = threadIdx.x;
    __shared__ float c1t[S * 130];  // C1 chunk with halo 1
    __shared__ float xsl[S * 128];  // h2 chunk
    const int ct = t % 50, rt = t / 50;     // GEMM map (t<250)
    const int c3p = t % 64, sg = t / 64;    // conv2: col pair base 2*c3p, wave-grp sg
    const int p0 = 2 * c3p;
    float acc[6][4];
    zacc<6>(acc);

    for (int ks = 0; ks < 8; ks++) {
        for (int idx = t; idx < S * 130; idx += 256) {
            int s = idx / 130, j = idx % 130;
            int gt = ks * 128 - 1 + j;
            c1t[idx] = (gt >= 0 && gt < TT) ? C1[(size_t)(b * S + s) * TT + gt] : 0.f;
        }
        __syncthreads();
        // conv2 + relu -> xsl: thread = 2 cols x 8 channels (ch = sg*8+m)
        {
            float a0[8], a1[8];
#pragma unroll
            for (int m = 0; m < 8; m++) {
                int ch = sg * 8 + m; int chc = ch < S ? ch : S - 1;
                a0[m] = bc2[chc]; a1[m] = bc2[chc];
            }
            for (int si = 0; si < S; si++) {
                float2 va = *(const float2*)(c1t + si * 130 + p0);
                float2 vb = *(const float2*)(c1t + si * 130 + p0 + 2);
#pragma unroll
                for (int m = 0; m < 8; m++) {
                    int ch = sg * 8 + m; int chc = ch < S ? ch : S - 1;
                    const float* w = Wc2 + chc * 90 + si * 3;
                    float w0 = w[0], w1 = w[1], w2 = w[2];
                    a0[m] = fmaf(w0, va.x, fmaf(w1, va.y, fmaf(w2, vb.x, a0[m])));
                    a1[m] = fmaf(w0, va.y, fmaf(w1, vb.x, fmaf(w2, vb.y, a1[m])));
                }
            }
#pragma unroll
            for (int m = 0; m < 8; m++) {
                int ch = sg * 8 + m;
                if (ch < S) {
                    float2 o = {fmaxf(a0[m], 0.f), fmaxf(a1[m], 0.f)};
                    *(float2*)(xsl + ch * 128 + p0) = o;
                }
            }
        }
        __syncthreads();
        if (t < 250)
            gemm_w4_pf<6, FD, 128>(xsl, 128, Wt + (size_t)ks * 128 * FD, ct, rt, acc);
        __syncthreads();
    }
    if (t < 250) {
#pragma unroll
        for (int m = 0; m < 6; m++) {
            int row = rt * 6 + m;
            float4 o;
            o.x = fmaxf(acc[m][0] + bt[4 * ct + 0], 0.f);
            o.y = fmaxf(acc[m][1] + bt[4 * ct + 1], 0.f);
            o.z = fmaxf(acc[m][2] + bt[4 * ct + 2], 0.f);
            o.w = fmaxf(acc[m][3] + bt[4 * ct + 3], 0.f);
            *(float4*)(F2 + (size_t)(b * S + row) * FD + 4 * ct) = o;
        }
    }
}

// ================= K3: k_att = AF + Gv(loc|glb) =================
__global__ __launch_bounds__(256) void k_att(
    const float* __restrict__ F2, const float* __restrict__ Wa,
    const float* __restrict__ adj, const float* __restrict__ Wl,
    const float* __restrict__ Wgl,
    float* __restrict__ AF, float* __restrict__ Gv) {
    const int b = blockIdx.x, t = threadIdx.x;
    __shared__ float A[32 * FD];     // F2, rows 30/31 zero
    __shared__ float Bu[32 * FD];    // staging
    __shared__ float scl[32 * 32];   // scores -> A_F (stride 32, pads zero)
    __shared__ float adjl[32 * 32];
    for (int idx = t; idx < 32 * FD; idx += 256) {
        A[idx] = (idx < S * FD) ? F2[(size_t)b * S * FD + idx] : 0.f;
        if (idx >= S * FD) Bu[idx] = 0.f;
    }
    for (int idx = t; idx < 1024; idx += 256) {
        int r = idx >> 5, cc = idx & 31;
        adjl[idx] = (r < S && cc < S) ? adj[r * S + cc] : 0.f;
        scl[idx] = 0.f;
    }
    __syncthreads();
    const int ct = t % 50, rt = t / 50;
    float acc[6][4];
    // P = F2 @ Wa -> Bu
    zacc<6>(acc);
    if (t < 250) {
        gemm_w4_pf<6, FD, FD>(A, FD, Wa, ct, rt, acc);
#pragma unroll
        for (int m = 0; m < 6; m++) {
            float4 o = {acc[m][0], acc[m][1], acc[m][2], acc[m][3]};
            *(float4*)(Bu + (rt * 6 + m) * FD + 4 * ct) = o;
        }
    }
    __syncthreads();
    // scl[i,j] = relu(P[i,:] . F2[j,:])
    for (int idx = t; idx < S * S; idx += 256) {
        int i = idx / S, j = idx % S;
        float a = 0.f;
        for (int f4 = 0; f4 < 50; f4++) {
            float4 p = *(const float4*)(Bu + i * FD + 4 * f4);
            float4 q = *(const float4*)(A + j * FD + 4 * f4);
            a = fmaf(p.x, q.x, a); a = fmaf(p.y, q.y, a);
            a = fmaf(p.z, q.z, a); a = fmaf(p.w, q.w, a);
        }
        scl[i * 32 + j] = fmaxf(a, 0.f);
    }
    __syncthreads();
    if (t < S) {
        float mx = -1e30f;
        for (int j = 0; j < S; j++) mx = fmaxf(mx, scl[t * 32 + j]);
        float den = 0.f;
        for (int j = 0; j < S; j++) den += expf(scl[t * 32 + j] - mx);
        float inv = 1.f / den;
        for (int j = 0; j < S; j++) scl[t * 32 + j] = expf(scl[t * 32 + j] - mx) * inv;
    }
    __syncthreads();
    for (int idx = t; idx < S * S; idx += 256)
        AF[(size_t)b * S * S + idx] = scl[(idx / S) * 32 + (idx % S)];
    // loc: T = adj@F2 -> Bu ; Gv[:, :150] = relu(T @ Wl)
    zacc<6>(acc);
    if (t < 250) gemm_a32<6>(adjl, A, FD, ct, rt, acc);
    __syncthreads();
    if (t < 250)
#pragma unroll
        for (int m = 0; m < 6; m++) {
            float4 o = {acc[m][0], acc[m][1], acc[m][2], acc[m][3]};
            *(float4*)(Bu + (rt * 6 + m) * FD + 4 * ct) = o;
        }
    __syncthreads();
    const int ct2 = t % 38, rt2 = t / 38;
    const bool full = (4 * ct2 + 2) < 150;
    const int off23 = full ? 2 : -2;
    if (t < 228) {
        float a2[5][4];
        zacc<5>(a2);
        gemm_w150_pf(Bu, Wl, ct2, rt2, a2, off23);
#pragma unroll
        for (int m = 0; m < 5; m++) {
            float* o = Gv + (size_t)(b * S + rt2 * 5 + m) * 300 + 4 * ct2;
            o[0] = fmaxf(a2[m][0], 0.f); o[1] = fmaxf(a2[m][1], 0.f);
            if (full) { o[2] = fmaxf(a2[m][2], 0.f); o[3] = fmaxf(a2[m][3], 0.f); }
        }
    }
    __syncthreads();
    // glb: T = AF@F2 -> Bu ; Gv[:, 150:] = relu(T @ Wgl)
    zacc<6>(acc);
    if (t < 250) gemm_a32<6>(scl, A, FD, ct, rt, acc);
    __syncthreads();
    if (t < 250)
#pragma unroll
        for (int m = 0; m < 6; m++) {
            float4 o = {acc[m][0], acc[m][1], acc[m][2], acc[m][3]};
            *(float4*)(Bu + (rt * 6 + m) * FD + 4 * ct) = o;
        }
    __syncthreads();
    if (t < 228) {
        float a2[5][4];
        zacc<5>(a2);
        gemm_w150_pf(Bu, Wgl, ct2, rt2, a2, off23);
#pragma unroll
        for (int m = 0; m < 5; m++) {
            float* o = Gv + (size_t)(b * S + rt2 * 5 + m) * 300 + 150 + 4 * ct2;
            o[0] = fmaxf(a2[m][0], 0.f); o[1] = fmaxf(a2[m][1], 0.f);
            if (full) { o[2] = fmaxf(a2[m][2], 0.f); o[3] = fmaxf(a2[m][3], 0.f); }
        }
    }
}

// ================= K4: k_mgcn = xs + X1..X3 + gates + Gh =================
__global__ __launch_bounds__(256) void k_mgcn(
    const float* __restrict__ F2, const float* __restrict__ AF,
    const float* __restrict__ adj,
    const float* __restrict__ Wg1, const float* __restrict__ Wg2,
    const float* __restrict__ Wm1, const float* __restrict__ Wm2,
    const float* __restrict__ Wm3, const float* __restrict__ wg,
    const float* __restrict__ Wp1, const float* __restrict__ Wp2,
    const float* __restrict__ Wp3, float* __restrict__ Gh) {
    const int b = blockIdx.x, t = threadIdx.x;
    __shared__ float A[32 * FD];     // X chain (starts as F2), rows 30/31 zero
    __shared__ float Bu[32 * FD];    // xs / T staging
    __shared__ float afl[32 * 32];   // AF, then adj*g_k (stride 32, pads zero)
    __shared__ float adjl[32 * 32];
    __shared__ float sk[96];
    __shared__ float gl[96];
    const int ct = t % 50, rt = t / 50;
    const int ct3 = t % 25, rt3 = t / 25;
    for (int idx = t; idx < 32 * FD; idx += 256) {
        A[idx] = (idx < S * FD) ? F2[(size_t)b * S * FD + idx] : 0.f;
        if (idx >= S * FD) Bu[idx] = 0.f;
    }
    for (int idx = t; idx < 1024; idx += 256) {
        int r = idx >> 5, cc = idx & 31;
        afl[idx] = (r < S && cc < S) ? AF[(size_t)b * S * S + r * S + cc] : 0.f;
        adjl[idx] = (r < S && cc < S) ? adj[r * S + cc] : 0.f;
    }
    if (t < 96) sk[t] = 0.f;
    __syncthreads();

    float acc[6][4];
#define STAGE_A(AL, XIN, XOUT)                                              \
    {                                                                       \
        zacc<6>(acc);                                                       \
        if (t < 250) gemm_a32<6>(AL, XIN, FD, ct, rt, acc);                 \
        __syncthreads();                                                    \
        if (t < 250) {                                                      \
            _Pragma("unroll")                                               \
            for (int m = 0; m < 6; m++) {                                   \
                float4 o = {acc[m][0], acc[m][1], acc[m][2], acc[m][3]};    \
                *(float4*)(XOUT + (rt * 6 + m) * FD + 4 * ct) = o;          \
            }                                                               \
        }                                                                   \
        __syncthreads();                                                    \
    }
#define STAGE_W(XIN, W, XOUT, RELU)                                         \
    {                                                                       \
        zacc<6>(acc);                                                       \
        if (t < 250) gemm_w4_pf<6, FD, FD>(XIN, FD, W, ct, rt, acc);        \
        __syncthreads();                                                    \
        if (t < 250) {                                                      \
            _Pragma("unroll")                                               \
            for (int m = 0; m < 6; m++) {                                   \
                float4 o;                                                   \
                o.x = RELU ? fmaxf(acc[m][0], 0.f) : acc[m][0];             \
                o.y = RELU ? fmaxf(acc[m][1], 0.f) : acc[m][1];             \
                o.z = RELU ? fmaxf(acc[m][2], 0.f) : acc[m][2];             \
                o.w = RELU ? fmaxf(acc[m][3], 0.f) : acc[m][3];             \
                *(float4*)(XOUT + (rt * 6 + m) * FD + 4 * ct) = o;          \
            }                                                               \
        }                                                                   \
        __syncthreads();                                                    \
    }

    // xs chain in Bu
    STAGE_A(adjl, A, Bu);
    STAGE_W(Bu, Wg1, Bu, true);
    STAGE_A(adjl, Bu, Bu);
    STAGE_W(Bu, Wg2, Bu, false);

    float h1r[6][4], h2r[6][4], h3r[6][4];
#define EXTRACT_H(HR, K)                                                    \
    {                                                                       \
        if (t < 250) {                                                      \
            _Pragma("unroll")                                               \
            for (int m = 0; m < 6; m++) {                                   \
                int row = rt * 6 + m;                                       \
                float4 xv = *(const float4*)(A + row * FD + 4 * ct);        \
                float4 sv = *(const float4*)(Bu + row * FD + 4 * ct);       \
                HR[m][0] = 0.5f * (xv.x + sv.x);                            \
                HR[m][1] = 0.5f * (xv.y + sv.y);                            \
                HR[m][2] = 0.5f * (xv.z + sv.z);                            \
                HR[m][3] = 0.5f * (xv.w + sv.w);                            \
                float p = HR[m][0] * wg[(4 * ct + 0) * 3 + K]               \
                        + HR[m][1] * wg[(4 * ct + 1) * 3 + K]               \
                        + HR[m][2] * wg[(4 * ct + 2) * 3 + K]               \
                        + HR[m][3] * wg[(4 * ct + 3) * 3 + K];              \
                atomicAdd(&sk[row * 3 + K], p);                             \
            }                                                               \
        }                                                                   \
        __syncthreads();                                                    \
    }

    STAGE_A(afl, A, A);
    STAGE_W(A, Wm1, A, true);
    EXTRACT_H(h1r, 0);
    STAGE_A(afl, A, A);
    STAGE_W(A, Wm2, A, true);
    EXTRACT_H(h2r, 1);
    STAGE_A(afl, A, A);
    STAGE_W(A, Wm3, A, true);
    EXTRACT_H(h3r, 2);

    if (t < S) {
        float a0 = sk[t * 3 + 0], a1 = sk[t * 3 + 1], a2 = sk[t * 3 + 2];
        float m = fmaxf(a0, fmaxf(a1, a2));
        float e0 = expf(a0 - m), e1 = expf(a1 - m), e2 = expf(a2 - m);
        float inv = 1.f / (e0 + e1 + e2);
        gl[t * 3 + 0] = e0 * inv; gl[t * 3 + 1] = e1 * inv; gl[t * 3 + 2] = e2 * inv;
    }
    __syncthreads();

#define GH_STAGE(HR, K, WP)                                                 \
    {                                                                       \
        if (t < 250) {                                                      \
            _Pragma("unroll")                                               \
            for (int m = 0; m < 6; m++) {                                   \
                float4 o = {HR[m][0], HR[m][1], HR[m][2], HR[m][3]};        \
                *(float4*)(A + (rt * 6 + m) * FD + 4 * ct) = o;             \
            }                                                               \
        }                                                                   \
        for (int idx = t; idx < 1024; idx += 256) {                         \
            int cc = idx & 31;                                              \
            afl[idx] = (cc < S) ? adjl[idx] * gl[cc * 3 + K] : 0.f;         \
        }                                                                   \
        __syncthreads();                                                    \
        STAGE_A(afl, A, Bu);                                                \
        if (t < 250) {                                                      \
            float a3[3][4];                                                 \
            zacc<3>(a3);                                                    \
            gemm_w4_pf<3, 100, FD>(Bu, FD, WP, ct3, rt3, a3);               \
            _Pragma("unroll")                                               \
            for (int m = 0; m < 3; m++) {                                   \
                float4 o = {a3[m][0], a3[m][1], a3[m][2], a3[m][3]};        \
                *(float4*)(Gh + (size_t)(b * S + rt3 * 3 + m) * 300 + K * 100 + 4 * ct3) = o; \
            }                                                               \
        }                                                                   \
        __syncthreads();                                                    \
    }
    GH_STAGE(h1r, 0, Wp1);
    GH_STAGE(h2r, 1, Wp2);
    GH_STAGE(h3r, 2, Wp3);
#undef STAGE_A
#undef STAGE_W
#undef EXTRACT_H
#undef GH_STAGE
}

// ================= K5: SE gates =================
__global__ __launch_bounds__(256) void k_se(const float* __restrict__ Gv, const float* __restrict__ Gh,
                                            const float* __restrict__ Ws1, const float* __restrict__ Ws2,
                                            const float* __restrict__ Wf1, const float* __restrict__ Wf2,
                                            float* __restrict__ wch, float* __restrict__ wft) {
    int b = blockIdx.x, t = threadIdx.x;
    __shared__ float mrow[S];
    __shared__ float u[15];
    __shared__ float mb[300];
    __shared__ float v[150];
    if (t < S) {
        float a = 0.f;
        const float* gp = Gv + ((size_t)b * S + t) * 300;
        for (int j = 0; j < 300; j++) a += gp[j];
        mrow[t] = a * (1.f / 300.f);
    }
    for (int j = t; j < 300; j += 256) {
        float a = 0.f;
        for (int s = 0; s < S; s++) a += Gh[(size_t)b * S * 300 + s * 300 + j];
        mb[j] = a * (1.f / S);
    }
    __syncthreads();
    if (t < 15) {
        float a = 0.f;
        for (int i = 0; i < S; i++) a += mrow[i] * Ws1[i * 15 + t];
        u[t] = fmaxf(a, 0.f);
    }
    if (t >= 64 && t < 64 + 150) {
        int h = t - 64;
        float a = 0.f;
        for (int j = 0; j < 300; j++) a += mb[j] * Wf1[j * 150 + h];
        v[h] = fmaxf(a, 0.f);
    }
    __syncthreads();
    if (t < S) {
        float a = 0.f;
        for (int h = 0; h < 15; h++) a += u[h] * Ws2[h * 30 + t];
        wch[b * S + t] = 1.f / (1.f + expf(-a));
    }
    for (int j = t; j < 300; j += 256) {
        float a = 0.f;
        for (int h = 0; h < 150; h++) a += v[h] * Wf2[h * 300 + j];
        wft[b * 300 + j] = 1.f / (1.f + expf(-a));
    }
}

// ================= K6: classifier + log_softmax =================
__global__ __launch_bounds__(256) void k_cls(const float* __restrict__ Gh, const float* __restrict__ Gv,
                                             const float* __restrict__ wch, const float* __restrict__ wft,
                                             const float* __restrict__ Wcls, const float* __restrict__ bcls,
                                             float* __restrict__ out) {
    const int b = blockIdx.x, t = threadIdx.x;
    __shared__ float red[NC][256];
    __shared__ float wftl[300];
    __shared__ float wchl[S];
    for (int j = t; j < 300; j += 256) wftl[j] = wft[(size_t)b * 300 + j];
    if (t < S) wchl[t] = wch[b * S + t];
    __syncthreads();
    float acc[NC];
#pragma unroll
    for (int c = 0; c < NC; c++) acc[c] = 0.f;
    for (int i = t; i < S * 600; i += 256) {
        int s = i / 600, j = i % 600;
        float gval = (j < 300)
            ? Gh[(size_t)b * S * 300 + s * 300 + j] * wchl[s]
            : Gv[(size_t)b * S * 300 + s * 300 + (j - 300)] * wftl[j - 300];
        const float* wr = Wcls + (size_t)i * NC;
#pragma unroll
        for (int c = 0; c < NC; c++) acc[c] = fmaf(gval, wr[c], acc[c]);
    }
#pragma unroll
    for (int c = 0; c < NC; c++) red[c][t] = acc[c];
    __syncthreads();
    for (int off = 128; off > 0; off >>= 1) {
        if (t < off) {
#pragma unroll
            for (int c = 0; c < NC; c++) red[c][t] += red[c][t + off];
        }
        __syncthreads();
    }
    if (t == 0) {
        float lg[NC];
        float mx = -1e30f;
#pragma unroll
        for (int c = 0; c < NC; c++) { lg[c] = red[c][0] + bcls[c]; mx = fmaxf(mx, lg[c]); }
        float den = 0.f;
#pragma unroll
        for (int c = 0; c < NC; c++) den += expf(lg[c] - mx);
        float lden = logf(den) + mx;
#pragma unroll
        for (int c = 0; c < NC; c++) out[b * NC + c] = lg[c] - lden;
    }
}

extern "C" void kernel_launch(void* const* d_in, const int* in_sizes, int n_in,
                              void* d_out, int out_size, void* d_ws, size_t ws_size,
                              hipStream_t stream) {
    const float* x    = (const float*)d_in[0];
    const float* adj  = (const float*)d_in[1];
    const float* Wc1  = (const float*)d_in[2];
    const float* bc1  = (const float*)d_in[3];
    const float* Wc2  = (const float*)d_in[4];
    const float* bc2  = (const float*)d_in[5];
    const float* Wt   = (const float*)d_in[6];
    const float* bt   = (const float*)d_in[7];
    const float* Wa   = (const float*)d_in[8];
    const float* Wm1  = (const float*)d_in[9];
    const float* Wm2  = (const float*)d_in[10];
    const float* Wm3  = (const float*)d_in[11];
    const float* Wg1  = (const float*)d_in[12];
    const float* Wg2  = (const float*)d_in[13];
    const float* wg   = (const float*)d_in[14];
    const float* Wp1  = (const float*)d_in[15];
    const float* Wp2  = (const float*)d_in[16];
    const float* Wp3  = (const float*)d_in[17];
    const float* Wl   = (const float*)d_in[18];
    const float* Wgl  = (const float*)d_in[19];
    const float* Ws1  = (const float*)d_in[20];
    const float* Ws2  = (const float*)d_in[21];
    const float* Wf1  = (const float*)d_in[22];
    const float* Wf2  = (const float*)d_in[23];
    const float* Wcls = (const float*)d_in[24];
    const float* bcls = (const float*)d_in[25];

    float* ws  = (float*)d_ws;
    float* C1  = ws + OFS_C1;
    float* F2  = ws + OFS_F2;
    float* AF  = ws + OFS_AF;
    float* GV  = ws + OFS_GV;
    float* GH  = ws + OFS_GH;
    float* WCH = ws + OFS_WCH;
    float* WFT = ws + OFS_WFT;
    float* out = (float*)d_out;

    k_conv1<<<dim3(4, BB), 128, 0, stream>>>(x, Wc1, bc1, C1);
    k_f2<<<BB, 256, 0, stream>>>(C1, Wc2, bc2, Wt, bt, F2);
    k_att<<<BB, 256, 0, stream>>>(F2, Wa, adj, Wl, Wgl, AF, GV);
    k_mgcn<<<BB, 256, 0, stream>>>(F2, AF, adj, Wg1, Wg2, Wm1, Wm2, Wm3, wg,
                                   Wp1, Wp2, Wp3, GH);
    k_se<<<BB, 256, 0, stream>>>(GV, GH, Ws1, Ws2, Wf1, Wf2, WCH, WFT);
    k_cls<<<BB, 256, 0, stream>>>(GH, GV, WCH, WFT, Wcls, bcls, out);
}